// Round 1
// baseline (983.996 us; speedup 1.0000x reference)
//
#include <hip/hip_runtime.h>

#define QP 2500
#define KP 1344
#define SCALE 0.088388347648318447f
#define LNEPS 1e-5f

// ---------- projection: x^T -> LayerNorm(D=128) -> @W(128x128)+bias ----------
__global__ __launch_bounds__(256) void proj_kernel(
    const float* __restrict__ in, int P,
    const float* __restrict__ lnw, const float* __restrict__ lnb,
    const float* __restrict__ W, const float* __restrict__ bias,
    float* __restrict__ out)
{
  __shared__ __align__(16) float xs[128][36];
  __shared__ float ps[8][33];
  __shared__ float pq[8][33];
  __shared__ float mu_s[32];
  __shared__ float rs_s[32];

  const int bn = blockIdx.y;
  const int p0 = blockIdx.x * 32;
  const int t  = threadIdx.x;

  const float* src = in + ((size_t)bn * 128) * P + p0;
  for (int idx = t; idx < 128 * 32; idx += 256) {
    int d = idx >> 5, p = idx & 31;
    float v = 0.f;
    if (p0 + p < P) v = src[(size_t)d * P + p];
    xs[d][p] = v;
  }
  __syncthreads();
  {
    int p = t & 31, c = t >> 5;
    float s = 0.f, s2 = 0.f;
    #pragma unroll
    for (int dd = 0; dd < 16; ++dd) {
      float v = xs[c * 16 + dd][p];
      s += v; s2 += v * v;
    }
    ps[c][p] = s; pq[c][p] = s2;
  }
  __syncthreads();
  if (t < 32) {
    float s = 0.f, s2 = 0.f;
    #pragma unroll
    for (int c = 0; c < 8; ++c) { s += ps[c][t]; s2 += pq[c][t]; }
    float mu = s * (1.f / 128.f);
    float var = s2 * (1.f / 128.f) - mu * mu;
    mu_s[t] = mu;
    rs_s[t] = rsqrtf(var + LNEPS);
  }
  __syncthreads();
  for (int idx = t; idx < 128 * 32; idx += 256) {
    int d = idx >> 5, p = idx & 31;
    xs[d][p] = (xs[d][p] - mu_s[p]) * rs_s[p] * lnw[d] + lnb[d];
  }
  __syncthreads();
  {
    const int j  = t & 127;
    const int rg = t >> 7;  // 0/1 -> rows rg*16 .. rg*16+15
    float acc[16];
    #pragma unroll
    for (int r = 0; r < 16; ++r) acc[r] = 0.f;
    for (int d0 = 0; d0 < 128; d0 += 8) {
      float w8[8];
      #pragma unroll
      for (int i = 0; i < 8; ++i) w8[i] = W[(d0 + i) * 128 + j];
      #pragma unroll
      for (int i = 0; i < 8; ++i) {
        const int d = d0 + i;
        const float w = w8[i];
        const float4 x0 = *(const float4*)&xs[d][rg * 16 + 0];
        const float4 x1 = *(const float4*)&xs[d][rg * 16 + 4];
        const float4 x2 = *(const float4*)&xs[d][rg * 16 + 8];
        const float4 x3 = *(const float4*)&xs[d][rg * 16 + 12];
        acc[0]  += x0.x * w; acc[1]  += x0.y * w; acc[2]  += x0.z * w; acc[3]  += x0.w * w;
        acc[4]  += x1.x * w; acc[5]  += x1.y * w; acc[6]  += x1.z * w; acc[7]  += x1.w * w;
        acc[8]  += x2.x * w; acc[9]  += x2.y * w; acc[10] += x2.z * w; acc[11] += x2.w * w;
        acc[12] += x3.x * w; acc[13] += x3.y * w; acc[14] += x3.z * w; acc[15] += x3.w * w;
      }
    }
    const float bj = bias[j];
    #pragma unroll
    for (int r = 0; r < 16; ++r) {
      int p = rg * 16 + r;
      if (p0 + p < P)
        out[((size_t)bn * P + p0 + p) * 128 + j] = acc[r] + bj;
    }
  }
}

// ---------- fused attention: per (b, h, 32-q tile), online softmax over NK=8064 ----------
__global__ __launch_bounds__(256) void attn_kernel(
    const float* __restrict__ qh, const float* __restrict__ kh,
    const float* __restrict__ vh, float* __restrict__ aout)
{
  __shared__ __align__(16) float qv[6][32][36];
  __shared__ __align__(16) float kt[64][36];
  __shared__ __align__(16) float vt[64][36];
  __shared__ __align__(16) float Ps[32][72];

  const int b = blockIdx.z, h = blockIdx.y, q0 = blockIdx.x * 32;
  const int t = threadIdx.x;
  const int q = t >> 3, g = t & 7, dh0 = g * 4;

  for (int idx = t; idx < 6 * 32 * 32; idx += 256) {
    int n = idx >> 10;
    int rem = idx & 1023;
    int qi = rem >> 5, dh = rem & 31;
    int qrow = q0 + qi;
    float v = 0.f;
    if (qrow < QP) v = qh[(((size_t)(b * 6 + n)) * QP + qrow) * 128 + h * 32 + dh];
    qv[n][qi][dh] = v;
  }
  float m_run = -1e30f, l_run = 0.f;
  float a0 = 0.f, a1 = 0.f, a2 = 0.f, a3 = 0.f;
  float4 qr[8];
  __syncthreads();

  for (int tile = 0; tile < 126; ++tile) {
    const int n  = tile / 21;
    const int kb = tile - n * 21;
    const int k0 = kb << 6;
    if (kb == 0) {
      #pragma unroll
      for (int d4 = 0; d4 < 8; ++d4) qr[d4] = *(const float4*)&qv[n][q][d4 * 4];
    }
    {
      const float* kbase = kh + (((size_t)(b * 6 + n)) * KP + k0) * 128 + h * 32;
      const float* vbase = vh + (((size_t)(b * 6 + n)) * KP + k0) * 128 + h * 32;
      for (int idx = t; idx < 64 * 32; idx += 256) {
        int kk = idx >> 5, dh = idx & 31;
        kt[kk][dh] = kbase[(size_t)kk * 128 + dh];
        vt[kk][dh] = vbase[(size_t)kk * 128 + dh];
      }
    }
    __syncthreads();
    // logits: this thread owns k = g + 8*j, j = 0..7
    float s[8];
    #pragma unroll
    for (int j = 0; j < 8; ++j) s[j] = 0.f;
    #pragma unroll
    for (int d4 = 0; d4 < 8; ++d4) {
      const float4 qq = qr[d4];
      #pragma unroll
      for (int j = 0; j < 8; ++j) {
        const float4 kv = *(const float4*)&kt[g + 8 * j][d4 * 4];
        s[j] += qq.x * kv.x + qq.y * kv.y + qq.z * kv.z + qq.w * kv.w;
      }
    }
    float lmax = -1e30f;
    #pragma unroll
    for (int j = 0; j < 8; ++j) { s[j] *= SCALE; lmax = fmaxf(lmax, s[j]); }
    lmax = fmaxf(lmax, __shfl_xor(lmax, 1));
    lmax = fmaxf(lmax, __shfl_xor(lmax, 2));
    lmax = fmaxf(lmax, __shfl_xor(lmax, 4));
    const float nm = fmaxf(m_run, lmax);
    const float corr = __expf(m_run - nm);
    m_run = nm;
    a0 *= corr; a1 *= corr; a2 *= corr; a3 *= corr;
    float lsum = 0.f;
    #pragma unroll
    for (int j = 0; j < 8; ++j) {
      float e = __expf(s[j] - nm);
      Ps[q][g + 8 * j] = e;
      lsum += e;
    }
    lsum += __shfl_xor(lsum, 1);
    lsum += __shfl_xor(lsum, 2);
    lsum += __shfl_xor(lsum, 4);
    l_run = l_run * corr + lsum;
    // PV: Ps row written/read only by this wave's 8 lanes -> in-order LDS pipe, no barrier
    #pragma unroll 4
    for (int kk4 = 0; kk4 < 16; ++kk4) {
      const float4 p4 = *(const float4*)&Ps[q][kk4 * 4];
      const float pe[4] = {p4.x, p4.y, p4.z, p4.w};
      #pragma unroll
      for (int u = 0; u < 4; ++u) {
        const float p = pe[u];
        const float4 vv = *(const float4*)&vt[kk4 * 4 + u][dh0];
        a0 += p * vv.x; a1 += p * vv.y; a2 += p * vv.z; a3 += p * vv.w;
      }
    }
    __syncthreads();
  }
  const float inv = 1.f / l_run;
  const int qrow = q0 + q;
  if (qrow < QP) {
    float4 r;
    r.x = a0 * inv; r.y = a1 * inv; r.z = a2 * inv; r.w = a3 * inv;
    *(float4*)&aout[((size_t)b * QP + qrow) * 128 + h * 32 + dh0] = r;
  }
}

// ---------- epilogue: a@wo+bo+skip^T -> LN -> MLP(gelu) -> +res -> LN -> transposed store ----------
__global__ __launch_bounds__(256) void epilogue_kernel(
    const float* __restrict__ a, const float* __restrict__ skip,
    const float* __restrict__ wo, const float* __restrict__ bo,
    const float* __restrict__ lnpw, const float* __restrict__ lnpb,
    const float* __restrict__ w1, const float* __restrict__ b1,
    const float* __restrict__ w2, const float* __restrict__ b2,
    const float* __restrict__ lnqw, const float* __restrict__ lnqb,
    float* __restrict__ out)
{
  __shared__ float xa[16][129];
  __shared__ float zn[16][129];
  __shared__ float ht[16][257];
  __shared__ float mu_s[16], rs_s[16];

  const int b = blockIdx.y;
  const int q0 = blockIdx.x * 16;
  const int t = threadIdx.x;

  for (int idx = t; idx < 16 * 128; idx += 256) {
    int r = idx >> 7, j = idx & 127;
    float v = 0.f;
    int qrow = q0 + r;
    if (qrow < QP) v = a[((size_t)b * QP + qrow) * 128 + j];
    xa[r][j] = v;
  }
  __syncthreads();
  // GEMM1: z = a@wo + bo + skip^T
  {
    const int j = t & 127;
    const int rg = t >> 7;  // rows rg*8 .. rg*8+7
    float acc[8];
    #pragma unroll
    for (int r = 0; r < 8; ++r) acc[r] = 0.f;
    for (int d0 = 0; d0 < 128; d0 += 8) {
      float w8[8];
      #pragma unroll
      for (int i = 0; i < 8; ++i) w8[i] = wo[(d0 + i) * 128 + j];
      #pragma unroll
      for (int i = 0; i < 8; ++i) {
        const float w = w8[i];
        #pragma unroll
        for (int r = 0; r < 8; ++r) acc[r] += xa[rg * 8 + r][d0 + i] * w;
      }
    }
    const float bj = bo[j];
    #pragma unroll
    for (int r = 0; r < 8; ++r) {
      int qrow = q0 + rg * 8 + r;
      float sv = 0.f;
      if (qrow < QP) sv = skip[((size_t)b * 128 + j) * QP + qrow];
      zn[rg * 8 + r][j] = acc[r] + bj + sv;
    }
  }
  __syncthreads();
  if (t < 16) {
    float s = 0.f, s2 = 0.f;
    for (int d = 0; d < 128; ++d) { float v = zn[t][d]; s += v; s2 += v * v; }
    float mu = s * (1.f / 128.f);
    float var = s2 * (1.f / 128.f) - mu * mu;
    mu_s[t] = mu; rs_s[t] = rsqrtf(var + LNEPS);
  }
  __syncthreads();
  for (int idx = t; idx < 16 * 128; idx += 256) {
    int r = idx >> 7, j = idx & 127;
    zn[r][j] = (zn[r][j] - mu_s[r]) * rs_s[r] * lnpw[j] + lnpb[j];
  }
  __syncthreads();
  // GEMM2: h = gelu(zn@w1 + b1)   (16 x 256)
  {
    const int j = t;  // 0..255
    float acc[16];
    #pragma unroll
    for (int r = 0; r < 16; ++r) acc[r] = 0.f;
    for (int d0 = 0; d0 < 128; d0 += 8) {
      float w8[8];
      #pragma unroll
      for (int i = 0; i < 8; ++i) w8[i] = w1[(d0 + i) * 256 + j];
      #pragma unroll
      for (int i = 0; i < 8; ++i) {
        const float w = w8[i];
        #pragma unroll
        for (int r = 0; r < 16; ++r) acc[r] += zn[r][d0 + i] * w;
      }
    }
    const float bj = b1[j];
    #pragma unroll
    for (int r = 0; r < 16; ++r) {
      float x = acc[r] + bj;
      ht[r][j] = 0.5f * x * (1.f + erff(x * 0.70710678118654752f));
    }
  }
  __syncthreads();
  // GEMM3: z2 = h@w2 + b2 + zn
  {
    const int j = t & 127;
    const int rg = t >> 7;
    float acc[8];
    #pragma unroll
    for (int r = 0; r < 8; ++r) acc[r] = 0.f;
    for (int d0 = 0; d0 < 256; d0 += 8) {
      float w8[8];
      #pragma unroll
      for (int i = 0; i < 8; ++i) w8[i] = w2[(d0 + i) * 128 + j];
      #pragma unroll
      for (int i = 0; i < 8; ++i) {
        const float w = w8[i];
        #pragma unroll
        for (int r = 0; r < 8; ++r) acc[r] += ht[rg * 8 + r][d0 + i] * w;
      }
    }
    const float bj = b2[j];
    #pragma unroll
    for (int r = 0; r < 8; ++r)
      xa[rg * 8 + r][j] = acc[r] + bj + zn[rg * 8 + r][j];
  }
  __syncthreads();
  if (t < 16) {
    float s = 0.f, s2 = 0.f;
    for (int d = 0; d < 128; ++d) { float v = xa[t][d]; s += v; s2 += v * v; }
    float mu = s * (1.f / 128.f);
    float var = s2 * (1.f / 128.f) - mu * mu;
    mu_s[t] = mu; rs_s[t] = rsqrtf(var + LNEPS);
  }
  __syncthreads();
  // final LN + transposed (coalesced over q) store
  for (int idx = t; idx < 16 * 128; idx += 256) {
    int j = idx >> 4, r = idx & 15;
    int qrow = q0 + r;
    if (qrow < QP) {
      float v = (xa[r][j] - mu_s[r]) * rs_s[r] * lnqw[j] + lnqb[j];
      out[((size_t)b * 128 + j) * QP + qrow] = v;
    }
  }
}

extern "C" void kernel_launch(void* const* d_in, const int* in_sizes, int n_in,
                              void* d_out, int out_size, void* d_ws, size_t ws_size,
                              hipStream_t stream) {
  const float* q       = (const float*)d_in[0];
  const float* k       = (const float*)d_in[1];
  const float* v       = (const float*)d_in[2];
  const float* skip    = (const float*)d_in[3];
  const float* ln_q_w  = (const float*)d_in[4];
  const float* ln_q_b  = (const float*)d_in[5];
  const float* wq      = (const float*)d_in[6];
  const float* bq      = (const float*)d_in[7];
  const float* ln_k_w  = (const float*)d_in[8];
  const float* ln_k_b  = (const float*)d_in[9];
  const float* wk      = (const float*)d_in[10];
  const float* bk      = (const float*)d_in[11];
  const float* ln_v_w  = (const float*)d_in[12];
  const float* ln_v_b  = (const float*)d_in[13];
  const float* wv      = (const float*)d_in[14];
  const float* bv      = (const float*)d_in[15];
  const float* wo      = (const float*)d_in[16];
  const float* bo      = (const float*)d_in[17];
  const float* ln_pre_w  = (const float*)d_in[18];
  const float* ln_pre_b  = (const float*)d_in[19];
  const float* w1      = (const float*)d_in[20];
  const float* b1      = (const float*)d_in[21];
  const float* w2      = (const float*)d_in[22];
  const float* b2      = (const float*)d_in[23];
  const float* ln_post_w = (const float*)d_in[24];
  const float* ln_post_b = (const float*)d_in[25];

  float* out = (float*)d_out;
  float* ws  = (float*)d_ws;
  float* qh = ws;                     // 2*6*2500*128 = 3,840,000 floats
  float* kh = qh + 3840000;           // 2*6*1344*128 = 2,064,384 floats
  float* vh = kh + 2064384;           // 2,064,384 floats
  float* aw = vh + 2064384;           // 2*2500*128   =   640,000 floats

  proj_kernel<<<dim3(79, 12), 256, 0, stream>>>(q, QP, ln_q_w, ln_q_b, wq, bq, qh);
  proj_kernel<<<dim3(42, 12), 256, 0, stream>>>(k, KP, ln_k_w, ln_k_b, wk, bk, kh);
  proj_kernel<<<dim3(42, 12), 256, 0, stream>>>(v, KP, ln_v_w, ln_v_b, wv, bv, vh);
  attn_kernel<<<dim3(79, 4, 2), 256, 0, stream>>>(qh, kh, vh, aw);
  epilogue_kernel<<<dim3(157, 2), 256, 0, stream>>>(aw, skip, wo, bo,
      ln_pre_w, ln_pre_b, w1, b1, w2, b2, ln_post_w, ln_post_b, out);
}

// Round 2
// 282.322 us; speedup vs baseline: 3.4854x; 3.4854x over previous
//
#include <hip/hip_runtime.h>

#define QP 2500
#define KP 1344
#define SCALE 0.088388347648318447f
#define LNEPS 1e-5f

typedef __attribute__((ext_vector_type(8))) short bf16x8;
typedef __attribute__((ext_vector_type(4))) float f32x4;

union FragU { ushort4 u[2]; bf16x8 f; };

__device__ inline bf16x8 ldfrag(const ushort* p) {
  FragU t;
  t.u[0] = *(const ushort4*)p;
  t.u[1] = *(const ushort4*)(p + 4);
  return t.f;
}

__device__ inline ushort f2bf(float x) {
  uint u = __float_as_uint(x);
  return (ushort)((u + 0x7fffu + ((u >> 16) & 1u)) >> 16);
}

// ---------- projection: x^T -> LayerNorm(D=128) -> @W(128x128)+bias -> bf16 (*oscale) ----------
__global__ __launch_bounds__(256) void proj_kernel(
    const float* __restrict__ in, int P,
    const float* __restrict__ lnw, const float* __restrict__ lnb,
    const float* __restrict__ W, const float* __restrict__ bias,
    ushort* __restrict__ out, float oscale)
{
  __shared__ __align__(16) float xs[128][36];
  __shared__ float ps[8][33];
  __shared__ float pq[8][33];
  __shared__ float mu_s[32];
  __shared__ float rs_s[32];

  const int bn = blockIdx.y;
  const int p0 = blockIdx.x * 32;
  const int t  = threadIdx.x;

  const float* src = in + ((size_t)bn * 128) * P + p0;
  for (int idx = t; idx < 128 * 32; idx += 256) {
    int d = idx >> 5, p = idx & 31;
    float v = 0.f;
    if (p0 + p < P) v = src[(size_t)d * P + p];
    xs[d][p] = v;
  }
  __syncthreads();
  {
    int p = t & 31, c = t >> 5;
    float s = 0.f, s2 = 0.f;
    #pragma unroll
    for (int dd = 0; dd < 16; ++dd) {
      float v = xs[c * 16 + dd][p];
      s += v; s2 += v * v;
    }
    ps[c][p] = s; pq[c][p] = s2;
  }
  __syncthreads();
  if (t < 32) {
    float s = 0.f, s2 = 0.f;
    #pragma unroll
    for (int c = 0; c < 8; ++c) { s += ps[c][t]; s2 += pq[c][t]; }
    float mu = s * (1.f / 128.f);
    float var = s2 * (1.f / 128.f) - mu * mu;
    mu_s[t] = mu;
    rs_s[t] = rsqrtf(var + LNEPS);
  }
  __syncthreads();
  for (int idx = t; idx < 128 * 32; idx += 256) {
    int d = idx >> 5, p = idx & 31;
    xs[d][p] = (xs[d][p] - mu_s[p]) * rs_s[p] * lnw[d] + lnb[d];
  }
  __syncthreads();
  {
    const int j  = t & 127;
    const int rg = t >> 7;
    float acc[16];
    #pragma unroll
    for (int r = 0; r < 16; ++r) acc[r] = 0.f;
    for (int d0 = 0; d0 < 128; d0 += 8) {
      float w8[8];
      #pragma unroll
      for (int i = 0; i < 8; ++i) w8[i] = W[(d0 + i) * 128 + j];
      #pragma unroll
      for (int i = 0; i < 8; ++i) {
        const int d = d0 + i;
        const float w = w8[i];
        const float4 x0 = *(const float4*)&xs[d][rg * 16 + 0];
        const float4 x1 = *(const float4*)&xs[d][rg * 16 + 4];
        const float4 x2 = *(const float4*)&xs[d][rg * 16 + 8];
        const float4 x3 = *(const float4*)&xs[d][rg * 16 + 12];
        acc[0]  += x0.x * w; acc[1]  += x0.y * w; acc[2]  += x0.z * w; acc[3]  += x0.w * w;
        acc[4]  += x1.x * w; acc[5]  += x1.y * w; acc[6]  += x1.z * w; acc[7]  += x1.w * w;
        acc[8]  += x2.x * w; acc[9]  += x2.y * w; acc[10] += x2.z * w; acc[11] += x2.w * w;
        acc[12] += x3.x * w; acc[13] += x3.y * w; acc[14] += x3.z * w; acc[15] += x3.w * w;
      }
    }
    const float bj = bias[j];
    #pragma unroll
    for (int r = 0; r < 16; ++r) {
      int p = rg * 16 + r;
      if (p0 + p < P)
        out[((size_t)bn * P + p0 + p) * 128 + j] = f2bf((acc[r] + bj) * oscale);
    }
  }
}

// ---------- MFMA flash attention over half the key space ----------
// block: 4 waves x 16 q rows = 64 q rows; grid (40, heads=4, b*2+half)
// writes unnormalized O + (m, l) per (q, h); combine happens in epilogue.
__global__ __launch_bounds__(256) void attn_kernel(
    const ushort* __restrict__ qh, const ushort* __restrict__ kh,
    const ushort* __restrict__ vh, float* __restrict__ aw,
    float* __restrict__ ml)
{
  __shared__ __align__(16) ushort Ks[64][40];      // [key][dh], pad 8
  __shared__ __align__(16) ushort Vt[32][72];      // [dh][key], pad 8
  __shared__ __align__(16) ushort Ps[4][16][72];   // per-wave P tile [q][key]

  const int q0   = blockIdx.x * 64;
  const int hh   = blockIdx.y;
  const int b    = blockIdx.z >> 1;
  const int half = blockIdx.z & 1;

  const int t    = threadIdx.x;
  const int w    = t >> 6;
  const int lane = t & 63;
  const int g    = lane >> 4;   // quarter 0..3
  const int ln15 = lane & 15;

  const f32x4 zf = {0.f, 0.f, 0.f, 0.f};
  f32x4 o0 = zf, o1 = zf;
  float m_run[4], l_run[4];
  #pragma unroll
  for (int r = 0; r < 4; ++r) { m_run[r] = -1e30f; l_run[r] = 0.f; }

  const int qrow_frag = q0 + w * 16 + ln15;

  for (int nn = 0; nn < 3; ++nn) {
    const int bn = b * 6 + half * 3 + nn;
    // Q fragment: A(16x32), lane holds row ln15, cols g*8..g*8+7
    bf16x8 qfrag;
    if (qrow_frag < QP)
      qfrag = *(const bf16x8*)&qh[((size_t)bn * QP + qrow_frag) * 128 + hh * 32 + g * 8];
    else {
      FragU z; z.u[0] = make_ushort4(0,0,0,0); z.u[1] = make_ushort4(0,0,0,0);
      qfrag = z.f;
    }

    const ushort* kbase = kh + ((size_t)bn * KP) * 128 + hh * 32;
    const ushort* vbase = vh + ((size_t)bn * KP) * 128 + hh * 32;

    for (int kt = 0; kt < 21; ++kt) {
      const int k0 = kt * 64;
      // ---- stage K (natural) and V (transposed) ----
      #pragma unroll
      for (int i = 0; i < 2; ++i) {
        int idx = t + i * 256;           // 0..511
        int kk = idx >> 3, dq = idx & 7;
        *(ushort4*)&Ks[kk][dq * 4] = *(const ushort4*)&kbase[(size_t)(k0 + kk) * 128 + dq * 4];
      }
      #pragma unroll
      for (int i = 0; i < 2; ++i) {
        int idx = t + i * 256;
        int kk = idx & 63, dh4 = idx >> 6;   // per wave: dh4 uniform -> conflict-free writes
        ushort4 v4 = *(const ushort4*)&vbase[(size_t)(k0 + kk) * 128 + dh4 * 4];
        Vt[dh4 * 4 + 0][kk] = v4.x;
        Vt[dh4 * 4 + 1][kk] = v4.y;
        Vt[dh4 * 4 + 2][kk] = v4.z;
        Vt[dh4 * 4 + 3][kk] = v4.w;
      }
      __syncthreads();

      // ---- QK^T: S(16x64) via 4 MFMAs ----
      f32x4 s[4];
      #pragma unroll
      for (int kb = 0; kb < 4; ++kb) {
        bf16x8 kf = ldfrag(&Ks[kb * 16 + ln15][g * 8]);
        s[kb] = __builtin_amdgcn_mfma_f32_16x16x32_bf16(qfrag, kf, zf, 0, 0, 0);
      }

      // ---- online softmax (scale pre-folded into qh) ----
      float mloc[4];
      #pragma unroll
      for (int r = 0; r < 4; ++r)
        mloc[r] = fmaxf(fmaxf(s[0][r], s[1][r]), fmaxf(s[2][r], s[3][r]));
      #pragma unroll
      for (int mk = 1; mk <= 8; mk <<= 1) {
        #pragma unroll
        for (int r = 0; r < 4; ++r)
          mloc[r] = fmaxf(mloc[r], __shfl_xor(mloc[r], mk));
      }
      #pragma unroll
      for (int r = 0; r < 4; ++r) {
        float mn = fmaxf(m_run[r], mloc[r]);
        float corr = __expf(m_run[r] - mn);
        m_run[r] = mn;
        l_run[r] *= corr;
        o0[r] *= corr;
        o1[r] *= corr;
      }
      #pragma unroll
      for (int kb = 0; kb < 4; ++kb) {
        #pragma unroll
        for (int r = 0; r < 4; ++r) {
          float e = __expf(s[kb][r] - m_run[r]);
          l_run[r] += e;
          Ps[w][g * 4 + r][kb * 16 + ln15] = f2bf(e);
        }
      }

      // ---- PV: O(16x32) += P(16x64) @ V(64x32), 4 MFMAs ----
      #pragma unroll
      for (int c = 0; c < 2; ++c) {
        bf16x8 pa = ldfrag(&Ps[w][ln15][c * 32 + g * 8]);
        bf16x8 v0 = ldfrag(&Vt[ln15][c * 32 + g * 8]);
        bf16x8 v1 = ldfrag(&Vt[16 + ln15][c * 32 + g * 8]);
        o0 = __builtin_amdgcn_mfma_f32_16x16x32_bf16(pa, v0, o0, 0, 0, 0);
        o1 = __builtin_amdgcn_mfma_f32_16x16x32_bf16(pa, v1, o1, 0, 0, 0);
      }
      __syncthreads();
    }
  }

  // final l reduce across the 16-lane group
  #pragma unroll
  for (int mk = 1; mk <= 8; mk <<= 1) {
    #pragma unroll
    for (int r = 0; r < 4; ++r)
      l_run[r] += __shfl_xor(l_run[r], mk);
  }

  #pragma unroll
  for (int r = 0; r < 4; ++r) {
    int qrow = q0 + w * 16 + g * 4 + r;
    if (qrow < QP) {
      size_t base = ((size_t)(half * 2 + b) * QP + qrow) * 128 + hh * 32;
      aw[base + ln15]      = o0[r];
      aw[base + 16 + ln15] = o1[r];
      if (ln15 == 0) {
        size_t mb = (((size_t)(half * 2 + b) * QP + qrow) * 4 + hh) * 2;
        ml[mb]     = m_run[r];
        ml[mb + 1] = l_run[r];
      }
    }
  }
}

// ---------- epilogue: combine halves -> a@wo+bo+skip^T -> LN -> MLP -> +res -> LN -> store^T ----------
__global__ __launch_bounds__(256) void epilogue_kernel(
    const float* __restrict__ aw, const float* __restrict__ ml,
    const float* __restrict__ skip,
    const float* __restrict__ wo, const float* __restrict__ bo,
    const float* __restrict__ lnpw, const float* __restrict__ lnpb,
    const float* __restrict__ w1, const float* __restrict__ b1,
    const float* __restrict__ w2, const float* __restrict__ b2,
    const float* __restrict__ lnqw, const float* __restrict__ lnqb,
    float* __restrict__ out)
{
  __shared__ float xa[16][129];
  __shared__ float zn[16][129];
  __shared__ float ht[16][257];
  __shared__ float mu_s[16], rs_s[16];
  __shared__ float cc0[16][4], cc1[16][4];

  const int b = blockIdx.y;
  const int q0 = blockIdx.x * 16;
  const int t = threadIdx.x;

  if (t < 64) {
    int r = t >> 2, h = t & 3;
    int qrow = q0 + r;
    float c0 = 0.f, c1 = 0.f;
    if (qrow < QP) {
      size_t i0 = (((size_t)b * QP + qrow) * 4 + h) * 2;
      size_t i1 = (((size_t)(2 + b) * QP + qrow) * 4 + h) * 2;
      float m0 = ml[i0], l0 = ml[i0 + 1];
      float m1 = ml[i1], l1 = ml[i1 + 1];
      float mm = fmaxf(m0, m1);
      float e0 = __expf(m0 - mm), e1 = __expf(m1 - mm);
      float inv = 1.f / (l0 * e0 + l1 * e1);
      c0 = e0 * inv; c1 = e1 * inv;
    }
    cc0[r][h] = c0; cc1[r][h] = c1;
  }
  __syncthreads();

  for (int idx = t; idx < 16 * 128; idx += 256) {
    int r = idx >> 7, j = idx & 127;
    float v = 0.f;
    int qrow = q0 + r;
    if (qrow < QP) {
      size_t i0 = ((size_t)b * QP + qrow) * 128 + j;
      size_t i1 = ((size_t)(2 + b) * QP + qrow) * 128 + j;
      int h = j >> 5;
      v = aw[i0] * cc0[r][h] + aw[i1] * cc1[r][h];
    }
    xa[r][j] = v;
  }
  __syncthreads();
  // GEMM1: z = a@wo + bo + skip^T
  {
    const int j = t & 127;
    const int rg = t >> 7;
    float acc[8];
    #pragma unroll
    for (int r = 0; r < 8; ++r) acc[r] = 0.f;
    for (int d0 = 0; d0 < 128; d0 += 8) {
      float w8[8];
      #pragma unroll
      for (int i = 0; i < 8; ++i) w8[i] = wo[(d0 + i) * 128 + j];
      #pragma unroll
      for (int i = 0; i < 8; ++i) {
        const float w = w8[i];
        #pragma unroll
        for (int r = 0; r < 8; ++r) acc[r] += xa[rg * 8 + r][d0 + i] * w;
      }
    }
    const float bj = bo[j];
    #pragma unroll
    for (int r = 0; r < 8; ++r) {
      int qrow = q0 + rg * 8 + r;
      float sv = 0.f;
      if (qrow < QP) sv = skip[((size_t)b * 128 + j) * QP + qrow];
      zn[rg * 8 + r][j] = acc[r] + bj + sv;
    }
  }
  __syncthreads();
  if (t < 16) {
    float s = 0.f, s2 = 0.f;
    for (int d = 0; d < 128; ++d) { float v = zn[t][d]; s += v; s2 += v * v; }
    float mu = s * (1.f / 128.f);
    float var = s2 * (1.f / 128.f) - mu * mu;
    mu_s[t] = mu; rs_s[t] = rsqrtf(var + LNEPS);
  }
  __syncthreads();
  for (int idx = t; idx < 16 * 128; idx += 256) {
    int r = idx >> 7, j = idx & 127;
    zn[r][j] = (zn[r][j] - mu_s[r]) * rs_s[r] * lnpw[j] + lnpb[j];
  }
  __syncthreads();
  // GEMM2: h = gelu(zn@w1 + b1)
  {
    const int j = t;
    float acc[16];
    #pragma unroll
    for (int r = 0; r < 16; ++r) acc[r] = 0.f;
    for (int d0 = 0; d0 < 128; d0 += 8) {
      float w8[8];
      #pragma unroll
      for (int i = 0; i < 8; ++i) w8[i] = w1[(d0 + i) * 256 + j];
      #pragma unroll
      for (int i = 0; i < 8; ++i) {
        const float w = w8[i];
        #pragma unroll
        for (int r = 0; r < 16; ++r) acc[r] += zn[r][d0 + i] * w;
      }
    }
    const float bj = b1[j];
    #pragma unroll
    for (int r = 0; r < 16; ++r) {
      float x = acc[r] + bj;
      ht[r][j] = 0.5f * x * (1.f + erff(x * 0.70710678118654752f));
    }
  }
  __syncthreads();
  // GEMM3: z2 = h@w2 + b2 + zn
  {
    const int j = t & 127;
    const int rg = t >> 7;
    float acc[8];
    #pragma unroll
    for (int r = 0; r < 8; ++r) acc[r] = 0.f;
    for (int d0 = 0; d0 < 256; d0 += 8) {
      float w8[8];
      #pragma unroll
      for (int i = 0; i < 8; ++i) w8[i] = w2[(d0 + i) * 128 + j];
      #pragma unroll
      for (int i = 0; i < 8; ++i) {
        const float w = w8[i];
        #pragma unroll
        for (int r = 0; r < 8; ++r) acc[r] += ht[rg * 8 + r][d0 + i] * w;
      }
    }
    const float bj = b2[j];
    #pragma unroll
    for (int r = 0; r < 8; ++r)
      xa[rg * 8 + r][j] = acc[r] + bj + zn[rg * 8 + r][j];
  }
  __syncthreads();
  if (t < 16) {
    float s = 0.f, s2 = 0.f;
    for (int d = 0; d < 128; ++d) { float v = xa[t][d]; s += v; s2 += v * v; }
    float mu = s * (1.f / 128.f);
    float var = s2 * (1.f / 128.f) - mu * mu;
    mu_s[t] = mu; rs_s[t] = rsqrtf(var + LNEPS);
  }
  __syncthreads();
  for (int idx = t; idx < 16 * 128; idx += 256) {
    int j = idx >> 4, r = idx & 15;
    int qrow = q0 + r;
    if (qrow < QP) {
      float v = (xa[r][j] - mu_s[r]) * rs_s[r] * lnqw[j] + lnqb[j];
      out[((size_t)b * 128 + j) * QP + qrow] = v;
    }
  }
}

extern "C" void kernel_launch(void* const* d_in, const int* in_sizes, int n_in,
                              void* d_out, int out_size, void* d_ws, size_t ws_size,
                              hipStream_t stream) {
  const float* q       = (const float*)d_in[0];
  const float* k       = (const float*)d_in[1];
  const float* v       = (const float*)d_in[2];
  const float* skip    = (const float*)d_in[3];
  const float* ln_q_w  = (const float*)d_in[4];
  const float* ln_q_b  = (const float*)d_in[5];
  const float* wq      = (const float*)d_in[6];
  const float* bq      = (const float*)d_in[7];
  const float* ln_k_w  = (const float*)d_in[8];
  const float* ln_k_b  = (const float*)d_in[9];
  const float* wk      = (const float*)d_in[10];
  const float* bk      = (const float*)d_in[11];
  const float* ln_v_w  = (const float*)d_in[12];
  const float* ln_v_b  = (const float*)d_in[13];
  const float* wv      = (const float*)d_in[14];
  const float* bv      = (const float*)d_in[15];
  const float* wo      = (const float*)d_in[16];
  const float* bo      = (const float*)d_in[17];
  const float* ln_pre_w  = (const float*)d_in[18];
  const float* ln_pre_b  = (const float*)d_in[19];
  const float* w1      = (const float*)d_in[20];
  const float* b1      = (const float*)d_in[21];
  const float* w2      = (const float*)d_in[22];
  const float* b2      = (const float*)d_in[23];
  const float* ln_post_w = (const float*)d_in[24];
  const float* ln_post_b = (const float*)d_in[25];

  float* out = (float*)d_out;
  ushort* qh = (ushort*)d_ws;              // 3,840,000 bf16
  ushort* kh = qh + 3840000;               // 2,064,384 bf16
  ushort* vh = kh + 2064384;               // 2,064,384 bf16
  float*  aw = (float*)(vh + 2064384);     // [half][b][q][128] = 1,280,000 f32
  float*  ml = aw + 1280000;               // [half][b][q][h][2] = 80,000 f32

  proj_kernel<<<dim3(79, 12), 256, 0, stream>>>(q, QP, ln_q_w, ln_q_b, wq, bq, qh, SCALE);
  proj_kernel<<<dim3(42, 12), 256, 0, stream>>>(k, KP, ln_k_w, ln_k_b, wk, bk, kh, 1.0f);
  proj_kernel<<<dim3(42, 12), 256, 0, stream>>>(v, KP, ln_v_w, ln_v_b, wv, bv, vh, 1.0f);
  attn_kernel<<<dim3(40, 4, 4), 256, 0, stream>>>(qh, kh, vh, aw, ml);
  epilogue_kernel<<<dim3(157, 2), 256, 0, stream>>>(aw, ml, skip, wo, bo,
      ln_pre_w, ln_pre_b, w1, b1, w2, b2, ln_post_w, ln_post_b, out);
}

// Round 3
// 237.424 us; speedup vs baseline: 4.1445x; 1.1891x over previous
//
#include <hip/hip_runtime.h>

#define QP 2500
#define KP 1344
#define SCALE 0.088388347648318447f
#define LOG2E 1.4426950408889634f
#define LNEPS 1e-5f

typedef __attribute__((ext_vector_type(8))) short bf16x8;
typedef __attribute__((ext_vector_type(4))) float f32x4;

__device__ inline ushort f2bf(float x) {
  uint u = __float_as_uint(x);
  return (ushort)((u + 0x7fffu + ((u >> 16) & 1u)) >> 16);
}

// row-dependent XOR swizzle on column byte offsets (bits 3..6)
__device__ inline int swz(int row) {
  return ((row & 7) << 4) | (((row >> 3) & 1) << 3);
}

union Frag8 { uint2 u[2]; bf16x8 f; ushort us[8]; };

__device__ inline bf16x8 ldfrag_swz(const char* rowbase, int colbyte, int C) {
  Frag8 t;
  t.u[0] = *(const uint2*)(rowbase + ((colbyte) ^ C));
  t.u[1] = *(const uint2*)(rowbase + ((colbyte + 8) ^ C));
  return t.f;
}

// ---------- projection: x^T -> LayerNorm(D=128) -> @W(128x128)+bias -> bf16 (*oscale) ----------
__global__ __launch_bounds__(256) void proj_kernel(
    const float* __restrict__ in, int P,
    const float* __restrict__ lnw, const float* __restrict__ lnb,
    const float* __restrict__ W, const float* __restrict__ bias,
    ushort* __restrict__ out, float oscale)
{
  __shared__ __align__(16) float xs[128][36];
  __shared__ float ps[8][33];
  __shared__ float pq[8][33];
  __shared__ float mu_s[32];
  __shared__ float rs_s[32];

  const int bn = blockIdx.y;
  const int p0 = blockIdx.x * 32;
  const int t  = threadIdx.x;

  const float* src = in + ((size_t)bn * 128) * P + p0;
  for (int idx = t; idx < 128 * 32; idx += 256) {
    int d = idx >> 5, p = idx & 31;
    float v = 0.f;
    if (p0 + p < P) v = src[(size_t)d * P + p];
    xs[d][p] = v;
  }
  __syncthreads();
  {
    int p = t & 31, c = t >> 5;
    float s = 0.f, s2 = 0.f;
    #pragma unroll
    for (int dd = 0; dd < 16; ++dd) {
      float v = xs[c * 16 + dd][p];
      s += v; s2 += v * v;
    }
    ps[c][p] = s; pq[c][p] = s2;
  }
  __syncthreads();
  if (t < 32) {
    float s = 0.f, s2 = 0.f;
    #pragma unroll
    for (int c = 0; c < 8; ++c) { s += ps[c][t]; s2 += pq[c][t]; }
    float mu = s * (1.f / 128.f);
    float var = s2 * (1.f / 128.f) - mu * mu;
    mu_s[t] = mu;
    rs_s[t] = rsqrtf(var + LNEPS);
  }
  __syncthreads();
  for (int idx = t; idx < 128 * 32; idx += 256) {
    int d = idx >> 5, p = idx & 31;
    xs[d][p] = (xs[d][p] - mu_s[p]) * rs_s[p] * lnw[d] + lnb[d];
  }
  __syncthreads();
  {
    const int j  = t & 127;
    const int rg = t >> 7;
    float acc[16];
    #pragma unroll
    for (int r = 0; r < 16; ++r) acc[r] = 0.f;
    for (int d0 = 0; d0 < 128; d0 += 8) {
      float w8[8];
      #pragma unroll
      for (int i = 0; i < 8; ++i) w8[i] = W[(d0 + i) * 128 + j];
      #pragma unroll
      for (int i = 0; i < 8; ++i) {
        const int d = d0 + i;
        const float w = w8[i];
        const float4 x0 = *(const float4*)&xs[d][rg * 16 + 0];
        const float4 x1 = *(const float4*)&xs[d][rg * 16 + 4];
        const float4 x2 = *(const float4*)&xs[d][rg * 16 + 8];
        const float4 x3 = *(const float4*)&xs[d][rg * 16 + 12];
        acc[0]  += x0.x * w; acc[1]  += x0.y * w; acc[2]  += x0.z * w; acc[3]  += x0.w * w;
        acc[4]  += x1.x * w; acc[5]  += x1.y * w; acc[6]  += x1.z * w; acc[7]  += x1.w * w;
        acc[8]  += x2.x * w; acc[9]  += x2.y * w; acc[10] += x2.z * w; acc[11] += x2.w * w;
        acc[12] += x3.x * w; acc[13] += x3.y * w; acc[14] += x3.z * w; acc[15] += x3.w * w;
      }
    }
    const float bj = bias[j];
    #pragma unroll
    for (int r = 0; r < 16; ++r) {
      int p = rg * 16 + r;
      if (p0 + p < P)
        out[((size_t)bn * P + p0 + p) * 128 + j] = f2bf((acc[r] + bj) * oscale);
    }
  }
}

// ---------- swapped-operand MFMA flash attention, 6-way key split ----------
// grid (20, 4, 12): 128 q rows/block (4 waves x 32), one (b,n) slab of 1344 keys.
// logits are in log2 domain (LOG2E folded into q projection).
__global__ __launch_bounds__(256) void attn_kernel(
    const ushort* __restrict__ qh, const ushort* __restrict__ kh,
    const ushort* __restrict__ vh, float* __restrict__ aw,
    float* __restrict__ ml)
{
  __shared__ __align__(16) ushort Vt[2][32][64];   // [buf][dh][key] swizzled
  __shared__ __align__(16) ushort Ps[4][32][64];   // [wave][q][key] swizzled

  const int q0 = blockIdx.x * 128;
  const int hh = blockIdx.y;
  const int bn = blockIdx.z;                       // b*6+n
  const int t = threadIdx.x;
  const int w = t >> 6, lane = t & 63;
  const int g = lane >> 4, ln15 = lane & 15;
  const int C = swz(ln15);                         // col swizzle for this lane's frag rows

  const size_t kvbase = ((size_t)bn * KP) * 128 + hh * 32;

  // ---- Q fragments (B-operand): lane holds Q[q=ln15(+16qh)][dh g*8..+7] ----
  bf16x8 qf[2];
  #pragma unroll
  for (int qh2 = 0; qh2 < 2; ++qh2) {
    int qrow = q0 + w * 32 + qh2 * 16 + ln15;
    if (qrow < QP)
      qf[qh2] = *(const bf16x8*)&qh[((size_t)bn * QP + qrow) * 128 + hh * 32 + g * 8];
    else {
      Frag8 z; z.u[0] = make_uint2(0, 0); z.u[1] = make_uint2(0, 0);
      qf[qh2] = z.f;
    }
  }

  // ---- prologue: stage V tile 0 ----
  #pragma unroll
  for (int i = 0; i < 2; ++i) {
    int dh4 = w + 4 * i;
    ushort4 v4 = *(const ushort4*)(vh + kvbase + (size_t)lane * 128 + dh4 * 4);
    #pragma unroll
    for (int u = 0; u < 4; ++u) {
      int row = dh4 * 4 + u;
      *(ushort*)((char*)Vt[0] + row * 128 + ((lane * 2) ^ swz(row))) = ((const ushort*)&v4)[u];
    }
  }
  __syncthreads();

  const f32x4 zf = {0.f, 0.f, 0.f, 0.f};
  f32x4 o[2][2] = {{zf, zf}, {zf, zf}};   // [qh][c]: q=4g+i(+16qh), dh=ln15+16c
  float m_run[2] = {-1e30f, -1e30f};
  float l_run[2] = {0.f, 0.f};            // per-lane partial (this lane's k slots)

  const ushort* kp0 = kh + kvbase + (size_t)ln15 * 128 + g * 8;

  for (int kt = 0; kt < 21; ++kt) {
    const int cur = kt & 1;
    const int k0n = (kt + 1) * 64;

    // ---- issue next-V global loads early (consumed after softmax) ----
    ushort4 vstg[2];
    if (kt < 20) {
      #pragma unroll
      for (int i = 0; i < 2; ++i) {
        int dh4 = w + 4 * i;
        vstg[i] = *(const ushort4*)(vh + kvbase + (size_t)(k0n + lane) * 128 + dh4 * 4);
      }
    }

    // ---- K fragments (A-operand) straight from global ----
    bf16x8 kf[4];
    #pragma unroll
    for (int kb = 0; kb < 4; ++kb)
      kf[kb] = *(const bf16x8*)(kp0 + (size_t)(kt * 64 + kb * 16) * 128);

    // ---- QK^T: S^T tiles; lane holds S[k=kb*16+4g+i][q=ln15(+16qh)] ----
    f32x4 s[2][4];
    #pragma unroll
    for (int kb = 0; kb < 4; ++kb) {
      s[0][kb] = __builtin_amdgcn_mfma_f32_16x16x32_bf16(kf[kb], qf[0], zf, 0, 0, 0);
      s[1][kb] = __builtin_amdgcn_mfma_f32_16x16x32_bf16(kf[kb], qf[1], zf, 0, 0, 0);
    }

    // ---- in-lane row max + cross-group reduce ----
    float sm[2];
    #pragma unroll
    for (int qh2 = 0; qh2 < 2; ++qh2) {
      float a = fmaxf(fmaxf(s[qh2][0][0], s[qh2][0][1]), fmaxf(s[qh2][0][2], s[qh2][0][3]));
      float b = fmaxf(fmaxf(s[qh2][1][0], s[qh2][1][1]), fmaxf(s[qh2][1][2], s[qh2][1][3]));
      float c = fmaxf(fmaxf(s[qh2][2][0], s[qh2][2][1]), fmaxf(s[qh2][2][2], s[qh2][2][3]));
      float d = fmaxf(fmaxf(s[qh2][3][0], s[qh2][3][1]), fmaxf(s[qh2][3][2], s[qh2][3][3]));
      float m = fmaxf(fmaxf(a, b), fmaxf(c, d));
      m = fmaxf(m, __shfl_xor(m, 16));
      m = fmaxf(m, __shfl_xor(m, 32));
      sm[qh2] = m;
    }

    // ---- defer-max rescale (THR = 8 in log2 units) ----
    bool need = (sm[0] > m_run[0] + 8.f) || (sm[1] > m_run[1] + 8.f);
    if (__any(need)) {
      float corr[2];
      #pragma unroll
      for (int qh2 = 0; qh2 < 2; ++qh2) {
        float mn = fmaxf(m_run[qh2], sm[qh2]);
        corr[qh2] = exp2f(m_run[qh2] - mn);
        m_run[qh2] = mn;
        l_run[qh2] *= corr[qh2];
      }
      #pragma unroll
      for (int qh2 = 0; qh2 < 2; ++qh2) {
        #pragma unroll
        for (int i = 0; i < 4; ++i) {
          float cb = __shfl(corr[qh2], 4 * g + i);   // corr lives at lane q=ln15
          o[qh2][0][i] *= cb;
          o[qh2][1][i] *= cb;
        }
      }
    }

    // ---- p = exp2(s - m), accumulate partial l, pack to bf16, write Ps ----
    #pragma unroll
    for (int qh2 = 0; qh2 < 2; ++qh2) {
      const int row = qh2 * 16 + ln15;
      char* prow = (char*)Ps[w] + row * 128;
      #pragma unroll
      for (int kb = 0; kb < 4; ++kb) {
        float e0 = exp2f(s[qh2][kb][0] - m_run[qh2]);
        float e1 = exp2f(s[qh2][kb][1] - m_run[qh2]);
        float e2 = exp2f(s[qh2][kb][2] - m_run[qh2]);
        float e3 = exp2f(s[qh2][kb][3] - m_run[qh2]);
        l_run[qh2] += (e0 + e1) + (e2 + e3);
        uint lo = ((__float_as_uint(e0) + 0x8000u) >> 16) | ((__float_as_uint(e1) + 0x8000u) & 0xffff0000u);
        uint hi = ((__float_as_uint(e2) + 0x8000u) >> 16) | ((__float_as_uint(e3) + 0x8000u) & 0xffff0000u);
        *(uint2*)(prow + ((kb * 32 + g * 8) ^ C)) = make_uint2(lo, hi);
      }
    }

    // ---- write next V tile into other buffer ----
    if (kt < 20) {
      #pragma unroll
      for (int i = 0; i < 2; ++i) {
        int dh4 = w + 4 * i;
        #pragma unroll
        for (int u = 0; u < 4; ++u) {
          int row = dh4 * 4 + u;
          *(ushort*)((char*)Vt[cur ^ 1] + row * 128 + ((lane * 2) ^ swz(row))) =
              ((const ushort*)&vstg[i])[u];
        }
      }
    }

    // ---- PV: O += P@V (A=P rows q, B=V^T rows dh) ----
    const char* p0r = (const char*)Ps[w] + (0 * 16 + ln15) * 128;
    const char* p1r = (const char*)Ps[w] + (1 * 16 + ln15) * 128;
    const char* v0r = (const char*)Vt[cur] + (0 * 16 + ln15) * 128;
    const char* v1r = (const char*)Vt[cur] + (1 * 16 + ln15) * 128;
    #pragma unroll
    for (int kc = 0; kc < 2; ++kc) {
      const int cb = kc * 64 + g * 16;
      bf16x8 pa0 = ldfrag_swz(p0r, cb, C);
      bf16x8 pa1 = ldfrag_swz(p1r, cb, C);
      bf16x8 vf0 = ldfrag_swz(v0r, cb, C);
      bf16x8 vf1 = ldfrag_swz(v1r, cb, C);
      o[0][0] = __builtin_amdgcn_mfma_f32_16x16x32_bf16(pa0, vf0, o[0][0], 0, 0, 0);
      o[0][1] = __builtin_amdgcn_mfma_f32_16x16x32_bf16(pa0, vf1, o[0][1], 0, 0, 0);
      o[1][0] = __builtin_amdgcn_mfma_f32_16x16x32_bf16(pa1, vf0, o[1][0], 0, 0, 0);
      o[1][1] = __builtin_amdgcn_mfma_f32_16x16x32_bf16(pa1, vf1, o[1][1], 0, 0, 0);
    }
    __syncthreads();
  }

  // ---- epilogue: reduce l across groups, store unnormalized O + (m, l) ----
  #pragma unroll
  for (int qh2 = 0; qh2 < 2; ++qh2) {
    float ls = l_run[qh2];
    ls += __shfl_xor(ls, 16);
    ls += __shfl_xor(ls, 32);
    int qq = q0 + w * 32 + qh2 * 16 + ln15;
    if (g == 0 && qq < QP)
      *(float2*)&ml[(((size_t)bn * QP + qq) * 4 + hh) * 2] = make_float2(m_run[qh2], ls);
    #pragma unroll
    for (int c = 0; c < 2; ++c) {
      #pragma unroll
      for (int i = 0; i < 4; ++i) {
        int qrow = q0 + w * 32 + qh2 * 16 + 4 * g + i;
        if (qrow < QP)
          aw[((size_t)bn * QP + qrow) * 128 + hh * 32 + c * 16 + ln15] = o[qh2][c][i];
      }
    }
  }
}

// ---------- epilogue: 6-way combine -> a@wo+bo+skip^T -> LN -> MLP -> +res -> LN -> store^T ----------
__global__ __launch_bounds__(256) void epilogue_kernel(
    const float* __restrict__ aw, const float* __restrict__ ml,
    const float* __restrict__ skip,
    const float* __restrict__ wo, const float* __restrict__ bo,
    const float* __restrict__ lnpw, const float* __restrict__ lnpb,
    const float* __restrict__ w1, const float* __restrict__ b1,
    const float* __restrict__ w2, const float* __restrict__ b2,
    const float* __restrict__ lnqw, const float* __restrict__ lnqb,
    float* __restrict__ out)
{
  __shared__ float xa[16][129];
  __shared__ float zn[16][129];
  __shared__ float ht[16][257];
  __shared__ float mu_s[16], rs_s[16];
  __shared__ float cc[16][4][6];

  const int b = blockIdx.y;
  const int q0 = blockIdx.x * 16;
  const int t = threadIdx.x;

  if (t < 64) {
    int r = t >> 2, h = t & 3;
    int qrow = q0 + r;
    if (qrow < QP) {
      float mv[6], lv[6], M = -1e30f;
      #pragma unroll
      for (int n = 0; n < 6; ++n) {
        float2 p = *(const float2*)&ml[(((size_t)(b * 6 + n) * QP + qrow) * 4 + h) * 2];
        mv[n] = p.x; lv[n] = p.y; M = fmaxf(M, p.x);
      }
      float wsum = 0.f, wv[6];
      #pragma unroll
      for (int n = 0; n < 6; ++n) { wv[n] = exp2f(mv[n] - M); wsum += wv[n] * lv[n]; }
      float inv = 1.f / wsum;
      #pragma unroll
      for (int n = 0; n < 6; ++n) cc[r][h][n] = wv[n] * inv;
    } else {
      #pragma unroll
      for (int n = 0; n < 6; ++n) cc[r][h][n] = 0.f;
    }
  }
  __syncthreads();

  for (int idx = t; idx < 16 * 128; idx += 256) {
    int r = idx >> 7, j = idx & 127;
    float v = 0.f;
    int qrow = q0 + r;
    if (qrow < QP) {
      int h = j >> 5;
      #pragma unroll
      for (int n = 0; n < 6; ++n)
        v += aw[((size_t)(b * 6 + n) * QP + qrow) * 128 + j] * cc[r][h][n];
    }
    xa[r][j] = v;
  }
  __syncthreads();
  // GEMM1: z = a@wo + bo + skip^T
  {
    const int j = t & 127;
    const int rg = t >> 7;
    float acc[8];
    #pragma unroll
    for (int r = 0; r < 8; ++r) acc[r] = 0.f;
    for (int d0 = 0; d0 < 128; d0 += 8) {
      float w8[8];
      #pragma unroll
      for (int i = 0; i < 8; ++i) w8[i] = wo[(d0 + i) * 128 + j];
      #pragma unroll
      for (int i = 0; i < 8; ++i) {
        const float w = w8[i];
        #pragma unroll
        for (int r = 0; r < 8; ++r) acc[r] += xa[rg * 8 + r][d0 + i] * w;
      }
    }
    const float bj = bo[j];
    #pragma unroll
    for (int r = 0; r < 8; ++r) {
      int qrow = q0 + rg * 8 + r;
      float sv = 0.f;
      if (qrow < QP) sv = skip[((size_t)b * 128 + j) * QP + qrow];
      zn[rg * 8 + r][j] = acc[r] + bj + sv;
    }
  }
  __syncthreads();
  if (t < 16) {
    float s = 0.f, s2 = 0.f;
    for (int d = 0; d < 128; ++d) { float v = zn[t][d]; s += v; s2 += v * v; }
    float mu = s * (1.f / 128.f);
    float var = s2 * (1.f / 128.f) - mu * mu;
    mu_s[t] = mu; rs_s[t] = rsqrtf(var + LNEPS);
  }
  __syncthreads();
  for (int idx = t; idx < 16 * 128; idx += 256) {
    int r = idx >> 7, j = idx & 127;
    zn[r][j] = (zn[r][j] - mu_s[r]) * rs_s[r] * lnpw[j] + lnpb[j];
  }
  __syncthreads();
  // GEMM2: h = gelu(zn@w1 + b1)
  {
    const int j = t;
    float acc[16];
    #pragma unroll
    for (int r = 0; r < 16; ++r) acc[r] = 0.f;
    for (int d0 = 0; d0 < 128; d0 += 8) {
      float w8[8];
      #pragma unroll
      for (int i = 0; i < 8; ++i) w8[i] = w1[(d0 + i) * 256 + j];
      #pragma unroll
      for (int i = 0; i < 8; ++i) {
        const float w = w8[i];
        #pragma unroll
        for (int r = 0; r < 16; ++r) acc[r] += zn[r][d0 + i] * w;
      }
    }
    const float bj = b1[j];
    #pragma unroll
    for (int r = 0; r < 16; ++r) {
      float x = acc[r] + bj;
      ht[r][j] = 0.5f * x * (1.f + erff(x * 0.70710678118654752f));
    }
  }
  __syncthreads();
  // GEMM3: z2 = h@w2 + b2 + zn
  {
    const int j = t & 127;
    const int rg = t >> 7;
    float acc[8];
    #pragma unroll
    for (int r = 0; r < 8; ++r) acc[r] = 0.f;
    for (int d0 = 0; d0 < 256; d0 += 8) {
      float w8[8];
      #pragma unroll
      for (int i = 0; i < 8; ++i) w8[i] = w2[(d0 + i) * 128 + j];
      #pragma unroll
      for (int i = 0; i < 8; ++i) {
        const float w = w8[i];
        #pragma unroll
        for (int r = 0; r < 8; ++r) acc[r] += ht[rg * 8 + r][d0 + i] * w;
      }
    }
    const float bj = b2[j];
    #pragma unroll
    for (int r = 0; r < 8; ++r)
      xa[rg * 8 + r][j] = acc[r] + bj + zn[rg * 8 + r][j];
  }
  __syncthreads();
  if (t < 16) {
    float s = 0.f, s2 = 0.f;
    for (int d = 0; d < 128; ++d) { float v = xa[t][d]; s += v; s2 += v * v; }
    float mu = s * (1.f / 128.f);
    float var = s2 * (1.f / 128.f) - mu * mu;
    mu_s[t] = mu; rs_s[t] = rsqrtf(var + LNEPS);
  }
  __syncthreads();
  for (int idx = t; idx < 16 * 128; idx += 256) {
    int j = idx >> 4, r = idx & 15;
    int qrow = q0 + r;
    if (qrow < QP) {
      float v = (xa[r][j] - mu_s[r]) * rs_s[r] * lnqw[j] + lnqb[j];
      out[((size_t)b * 128 + j) * QP + qrow] = v;
    }
  }
}

extern "C" void kernel_launch(void* const* d_in, const int* in_sizes, int n_in,
                              void* d_out, int out_size, void* d_ws, size_t ws_size,
                              hipStream_t stream) {
  const float* q       = (const float*)d_in[0];
  const float* k       = (const float*)d_in[1];
  const float* v       = (const float*)d_in[2];
  const float* skip    = (const float*)d_in[3];
  const float* ln_q_w  = (const float*)d_in[4];
  const float* ln_q_b  = (const float*)d_in[5];
  const float* wq      = (const float*)d_in[6];
  const float* bq      = (const float*)d_in[7];
  const float* ln_k_w  = (const float*)d_in[8];
  const float* ln_k_b  = (const float*)d_in[9];
  const float* wk      = (const float*)d_in[10];
  const float* bk      = (const float*)d_in[11];
  const float* ln_v_w  = (const float*)d_in[12];
  const float* ln_v_b  = (const float*)d_in[13];
  const float* wv      = (const float*)d_in[14];
  const float* bv      = (const float*)d_in[15];
  const float* wo      = (const float*)d_in[16];
  const float* bo      = (const float*)d_in[17];
  const float* ln_pre_w  = (const float*)d_in[18];
  const float* ln_pre_b  = (const float*)d_in[19];
  const float* w1      = (const float*)d_in[20];
  const float* b1      = (const float*)d_in[21];
  const float* w2      = (const float*)d_in[22];
  const float* b2      = (const float*)d_in[23];
  const float* ln_post_w = (const float*)d_in[24];
  const float* ln_post_b = (const float*)d_in[25];

  float* out = (float*)d_out;
  ushort* qhp = (ushort*)d_ws;             // 3,840,000 bf16
  ushort* khp = qhp + 3840000;             // 2,064,384 bf16
  ushort* vhp = khp + 2064384;             // 2,064,384 bf16
  float*  aw  = (float*)(vhp + 2064384);   // [bn][q][128] = 12*2500*128 f32
  float*  ml  = aw + 3840000;              // [bn][q][h][2] = 240,000 f32

  proj_kernel<<<dim3(79, 12), 256, 0, stream>>>(q, QP, ln_q_w, ln_q_b, wq, bq, qhp, SCALE * LOG2E);
  proj_kernel<<<dim3(42, 12), 256, 0, stream>>>(k, KP, ln_k_w, ln_k_b, wk, bk, khp, 1.0f);
  proj_kernel<<<dim3(42, 12), 256, 0, stream>>>(v, KP, ln_v_w, ln_v_b, wv, bv, vhp, 1.0f);
  attn_kernel<<<dim3(20, 4, 12), 256, 0, stream>>>(qhp, khp, vhp, aw, ml);
  epilogue_kernel<<<dim3(157, 2), 256, 0, stream>>>(aw, ml, skip, wo, bo,
      ln_pre_w, ln_pre_b, w1, b1, w2, b2, ln_post_w, ln_post_b, out);
}

// Round 4
// 229.545 us; speedup vs baseline: 4.2867x; 1.0343x over previous
//
#include <hip/hip_runtime.h>

#define QP 2500
#define KP 1344
#define SCALE 0.088388347648318447f
#define LOG2E 1.4426950408889634f
#define LNEPS 1e-5f

typedef __attribute__((ext_vector_type(8))) short bf16x8;
typedef __attribute__((ext_vector_type(4))) float f32x4;

__device__ inline ushort f2bf(float x) {
  uint u = __float_as_uint(x);
  return (ushort)((u + 0x7fffu + ((u >> 16) & 1u)) >> 16);
}

// row-dependent XOR swizzle on column byte offsets (bits 3..6)
__device__ inline int swz(int row) {
  return ((row & 7) << 4) | (((row >> 3) & 1) << 3);
}

union Frag8 { uint2 u[2]; bf16x8 f; ushort us[8]; };

__device__ inline bf16x8 ldfrag_swz(const char* rowbase, int colbyte, int C) {
  Frag8 t;
  t.u[0] = *(const uint2*)(rowbase + ((colbyte) ^ C));
  t.u[1] = *(const uint2*)(rowbase + ((colbyte + 8) ^ C));
  return t.f;
}

// ---------- prep: W (128x128 f32, [k][j]) -> WT (128x128 bf16, [j][k]) ----------
__global__ __launch_bounds__(256) void wprep_kernel(
    const float* __restrict__ W, ushort* __restrict__ WT)
{
  const int t = threadIdx.x;
  const int idx = blockIdx.x * 1024 + t * 4;
  const int k = idx >> 7, j0 = idx & 127;
  float4 rd = *(const float4*)&W[idx];
  WT[(j0 + 0) * 128 + k] = f2bf(rd.x);
  WT[(j0 + 1) * 128 + k] = f2bf(rd.y);
  WT[(j0 + 2) * 128 + k] = f2bf(rd.z);
  WT[(j0 + 3) * 128 + k] = f2bf(rd.w);
}

// ---------- MFMA projection: x^T -> LayerNorm(D=128) -> @W(128x128)+bias -> bf16 ----------
// block: 256 threads, tile 64 positions x 128 outputs; 4 waves x (16 rows x 128 cols)
__global__ __launch_bounds__(256) void proj_kernel(
    const float* __restrict__ in, int P,
    const float* __restrict__ lnw, const float* __restrict__ lnb,
    const ushort* __restrict__ WT, const float* __restrict__ bias,
    ushort* __restrict__ out, float oscale)
{
  __shared__ __align__(16) ushort xb[64][128];    // LN'd X, swizzled
  __shared__ __align__(16) ushort wt[128][128];   // W^T, swizzled
  __shared__ float ps[4][64], pq[4][64];
  __shared__ float mu_s[64], rs_s[64];

  const int bn = blockIdx.y;
  const int p0 = blockIdx.x * 64;
  const int t  = threadIdx.x;
  const int w = t >> 6, lane = t & 63, g = lane >> 4, ln15 = lane & 15;

  // ---- stage W^T into LDS (swizzled, b128 writes) ----
  #pragma unroll
  for (int i = 0; i < 8; ++i) {
    int idx8 = t + 256 * i;                 // 0..2047
    int j = idx8 >> 4, ck = (idx8 & 15) * 16;
    *(uint4*)((char*)wt + j * 256 + (ck ^ ((j & 7) << 4))) =
        *(const uint4*)((const char*)WT + j * 256 + ck);
  }

  // ---- load X^T tile, keep in registers, compute LN stats ----
  const float* src = in + ((size_t)bn * 128) * P + p0;
  const int p = t & 63, dq = t >> 6;
  float xv[32];
  float s = 0.f, s2 = 0.f;
  #pragma unroll
  for (int kk = 0; kk < 32; ++kk) {
    int d = dq + 4 * kk;
    float v = (p0 + p < P) ? src[(size_t)d * P + p] : 0.f;
    xv[kk] = v; s += v; s2 += v * v;
  }
  ps[dq][p] = s; pq[dq][p] = s2;
  __syncthreads();
  if (t < 64) {
    float a = ps[0][t] + ps[1][t] + ps[2][t] + ps[3][t];
    float b = pq[0][t] + pq[1][t] + pq[2][t] + pq[3][t];
    float mu = a * (1.f / 128.f);
    float var = b * (1.f / 128.f) - mu * mu;
    mu_s[t] = mu; rs_s[t] = rsqrtf(var + LNEPS);
  }
  __syncthreads();
  {
    const float mu = mu_s[p], rs = rs_s[p];
    const int CW = (p & 7) << 4;
    #pragma unroll
    for (int kk = 0; kk < 32; ++kk) {
      int d = dq + 4 * kk;
      float v = (xv[kk] - mu) * rs * lnw[d] + lnb[d];
      *(ushort*)((char*)xb + p * 256 + ((2 * d) ^ CW)) = f2bf(v);
    }
  }
  __syncthreads();

  // ---- GEMM: [16 rows x 128 cols] per wave via MFMA ----
  const int prow = w * 16 + ln15;
  const char* xrow = (const char*)xb + prow * 256;
  const int CX = (prow & 7) << 4;
  const int CB = (ln15 & 7) << 4;
  const f32x4 zf = {0.f, 0.f, 0.f, 0.f};
  f32x4 acc[8];
  #pragma unroll
  for (int jc = 0; jc < 8; ++jc) acc[jc] = zf;

  #pragma unroll
  for (int ks = 0; ks < 4; ++ks) {
    bf16x8 a = ldfrag_swz(xrow, ks * 64 + g * 16, CX);
    #pragma unroll
    for (int jc = 0; jc < 8; ++jc) {
      bf16x8 b = ldfrag_swz((const char*)wt + (jc * 16 + ln15) * 256, ks * 64 + g * 16, CB);
      acc[jc] = __builtin_amdgcn_mfma_f32_16x16x32_bf16(a, b, acc[jc], 0, 0, 0);
    }
  }

  // ---- epilogue: +bias, *oscale, bf16 store ----
  #pragma unroll
  for (int jc = 0; jc < 8; ++jc) {
    const float bj = bias[jc * 16 + ln15];
    #pragma unroll
    for (int r = 0; r < 4; ++r) {
      int pr = p0 + w * 16 + 4 * g + r;
      if (pr < P)
        out[((size_t)bn * P + pr) * 128 + jc * 16 + ln15] = f2bf((acc[jc][r] + bj) * oscale);
    }
  }
}

// ---------- swapped-operand MFMA flash attention, 6-way key split ----------
// grid (40, 4, 12): 64 q rows/block (4 waves x 16), one (b,n) slab of 1344 keys.
__global__ __launch_bounds__(256) void attn_kernel(
    const ushort* __restrict__ qh, const ushort* __restrict__ kh,
    const ushort* __restrict__ vh, float* __restrict__ aw,
    float* __restrict__ ml)
{
  __shared__ __align__(16) ushort Vt[2][32][64];   // [buf][dh][key] swizzled
  __shared__ __align__(16) ushort Ps[4][16][64];   // [wave][q][key] swizzled

  const int q0 = blockIdx.x * 64;
  const int hh = blockIdx.y;
  const int bn = blockIdx.z;
  const int t = threadIdx.x;
  const int w = t >> 6, lane = t & 63;
  const int g = lane >> 4, ln15 = lane & 15;
  const int C = swz(ln15);

  const size_t kvbase = ((size_t)bn * KP) * 128 + hh * 32;

  // ---- Q fragment (B-operand): lane holds Q[q=ln15][dh g*8..+7] ----
  bf16x8 qf;
  {
    int qrow = q0 + w * 16 + ln15;
    if (qrow < QP)
      qf = *(const bf16x8*)&qh[((size_t)bn * QP + qrow) * 128 + hh * 32 + g * 8];
    else {
      Frag8 z; z.u[0] = make_uint2(0, 0); z.u[1] = make_uint2(0, 0);
      qf = z.f;
    }
  }

  // ---- prologue: stage V tile 0 ----
  #pragma unroll
  for (int i = 0; i < 2; ++i) {
    int dh4 = w + 4 * i;
    ushort4 v4 = *(const ushort4*)(vh + kvbase + (size_t)lane * 128 + dh4 * 4);
    #pragma unroll
    for (int u = 0; u < 4; ++u) {
      int row = dh4 * 4 + u;
      *(ushort*)((char*)Vt[0] + row * 128 + ((lane * 2) ^ swz(row))) = ((const ushort*)&v4)[u];
    }
  }
  __syncthreads();

  const f32x4 zf = {0.f, 0.f, 0.f, 0.f};
  f32x4 o[2] = {zf, zf};                 // [c]: q=4g+i, dh=ln15+16c
  float m_run = -1e30f;
  float l_run = 0.f;                     // per-lane partial

  const ushort* kp0 = kh + kvbase + (size_t)ln15 * 128 + g * 8;

  for (int kt = 0; kt < 21; ++kt) {
    const int cur = kt & 1;
    const int k0n = (kt + 1) * 64;

    // ---- issue next-V global loads early ----
    ushort4 vstg[2];
    if (kt < 20) {
      #pragma unroll
      for (int i = 0; i < 2; ++i) {
        int dh4 = w + 4 * i;
        vstg[i] = *(const ushort4*)(vh + kvbase + (size_t)(k0n + lane) * 128 + dh4 * 4);
      }
    }

    // ---- K fragments (A-operand) straight from global ----
    bf16x8 kf[4];
    #pragma unroll
    for (int kb = 0; kb < 4; ++kb)
      kf[kb] = *(const bf16x8*)(kp0 + (size_t)(kt * 64 + kb * 16) * 128);

    // ---- QK^T: lane holds S[k=kb*16+4g+i][q=ln15] ----
    f32x4 s[4];
    #pragma unroll
    for (int kb = 0; kb < 4; ++kb)
      s[kb] = __builtin_amdgcn_mfma_f32_16x16x32_bf16(kf[kb], qf, zf, 0, 0, 0);

    // ---- row max ----
    float sm;
    {
      float a = fmaxf(fmaxf(s[0][0], s[0][1]), fmaxf(s[0][2], s[0][3]));
      float b = fmaxf(fmaxf(s[1][0], s[1][1]), fmaxf(s[1][2], s[1][3]));
      float c = fmaxf(fmaxf(s[2][0], s[2][1]), fmaxf(s[2][2], s[2][3]));
      float d = fmaxf(fmaxf(s[3][0], s[3][1]), fmaxf(s[3][2], s[3][3]));
      float m = fmaxf(fmaxf(a, b), fmaxf(c, d));
      m = fmaxf(m, __shfl_xor(m, 16));
      m = fmaxf(m, __shfl_xor(m, 32));
      sm = m;
    }

    // ---- defer-max rescale (THR = 8 in log2 units) ----
    if (__any(sm > m_run + 8.f)) {
      float mn = fmaxf(m_run, sm);
      float corr = exp2f(m_run - mn);
      m_run = mn;
      l_run *= corr;
      #pragma unroll
      for (int i = 0; i < 4; ++i) {
        float cb = __shfl(corr, 4 * g + i);
        o[0][i] *= cb;
        o[1][i] *= cb;
      }
    }

    // ---- p = exp2(s - m), partial l, pack bf16, write Ps ----
    {
      char* prow = (char*)Ps[w] + ln15 * 128;
      #pragma unroll
      for (int kb = 0; kb < 4; ++kb) {
        float e0 = exp2f(s[kb][0] - m_run);
        float e1 = exp2f(s[kb][1] - m_run);
        float e2 = exp2f(s[kb][2] - m_run);
        float e3 = exp2f(s[kb][3] - m_run);
        l_run += (e0 + e1) + (e2 + e3);
        uint lo = ((__float_as_uint(e0) + 0x8000u) >> 16) | ((__float_as_uint(e1) + 0x8000u) & 0xffff0000u);
        uint hi = ((__float_as_uint(e2) + 0x8000u) >> 16) | ((__float_as_uint(e3) + 0x8000u) & 0xffff0000u);
        *(uint2*)(prow + ((kb * 32 + g * 8) ^ C)) = make_uint2(lo, hi);
      }
    }

    // ---- write next V tile ----
    if (kt < 20) {
      #pragma unroll
      for (int i = 0; i < 2; ++i) {
        int dh4 = w + 4 * i;
        #pragma unroll
        for (int u = 0; u < 4; ++u) {
          int row = dh4 * 4 + u;
          *(ushort*)((char*)Vt[cur ^ 1] + row * 128 + ((lane * 2) ^ swz(row))) =
              ((const ushort*)&vstg[i])[u];
        }
      }
    }

    // ---- PV: O += P@V ----
    const char* pr = (const char*)Ps[w] + ln15 * 128;
    const char* v0r = (const char*)Vt[cur] + ln15 * 128;
    const char* v1r = (const char*)Vt[cur] + (16 + ln15) * 128;
    #pragma unroll
    for (int kc = 0; kc < 2; ++kc) {
      const int cb = kc * 64 + g * 16;
      bf16x8 pa  = ldfrag_swz(pr,  cb, C);
      bf16x8 vf0 = ldfrag_swz(v0r, cb, C);
      bf16x8 vf1 = ldfrag_swz(v1r, cb, C);
      o[0] = __builtin_amdgcn_mfma_f32_16x16x32_bf16(pa, vf0, o[0], 0, 0, 0);
      o[1] = __builtin_amdgcn_mfma_f32_16x16x32_bf16(pa, vf1, o[1], 0, 0, 0);
    }
    __syncthreads();
  }

  // ---- epilogue: reduce l, store unnormalized O + (m, l) ----
  {
    float ls = l_run;
    ls += __shfl_xor(ls, 16);
    ls += __shfl_xor(ls, 32);
    int qq = q0 + w * 16 + ln15;
    if (g == 0 && qq < QP)
      *(float2*)&ml[(((size_t)bn * QP + qq) * 4 + hh) * 2] = make_float2(m_run, ls);
    #pragma unroll
    for (int c = 0; c < 2; ++c) {
      #pragma unroll
      for (int i = 0; i < 4; ++i) {
        int qrow = q0 + w * 16 + 4 * g + i;
        if (qrow < QP)
          aw[((size_t)bn * QP + qrow) * 128 + hh * 32 + c * 16 + ln15] = o[c][i];
      }
    }
  }
}

// ---------- epilogue: 6-way combine -> a@wo+bo+skip^T -> LN -> MLP -> +res -> LN -> store^T ----------
__global__ __launch_bounds__(256) void epilogue_kernel(
    const float* __restrict__ aw, const float* __restrict__ ml,
    const float* __restrict__ skip,
    const float* __restrict__ wo, const float* __restrict__ bo,
    const float* __restrict__ lnpw, const float* __restrict__ lnpb,
    const float* __restrict__ w1, const float* __restrict__ b1,
    const float* __restrict__ w2, const float* __restrict__ b2,
    const float* __restrict__ lnqw, const float* __restrict__ lnqb,
    float* __restrict__ out)
{
  __shared__ float xa[16][129];
  __shared__ float zn[16][129];
  __shared__ float ht[16][257];
  __shared__ float mu_s[16], rs_s[16];
  __shared__ float cc[16][4][6];

  const int b = blockIdx.y;
  const int q0 = blockIdx.x * 16;
  const int t = threadIdx.x;

  if (t < 64) {
    int r = t >> 2, h = t & 3;
    int qrow = q0 + r;
    if (qrow < QP) {
      float mv[6], lv[6], M = -1e30f;
      #pragma unroll
      for (int n = 0; n < 6; ++n) {
        float2 p = *(const float2*)&ml[(((size_t)(b * 6 + n) * QP + qrow) * 4 + h) * 2];
        mv[n] = p.x; lv[n] = p.y; M = fmaxf(M, p.x);
      }
      float wsum = 0.f, wv[6];
      #pragma unroll
      for (int n = 0; n < 6; ++n) { wv[n] = exp2f(mv[n] - M); wsum += wv[n] * lv[n]; }
      float inv = 1.f / wsum;
      #pragma unroll
      for (int n = 0; n < 6; ++n) cc[r][h][n] = wv[n] * inv;
    } else {
      #pragma unroll
      for (int n = 0; n < 6; ++n) cc[r][h][n] = 0.f;
    }
  }
  __syncthreads();

  for (int idx = t; idx < 16 * 128; idx += 256) {
    int r = idx >> 7, j = idx & 127;
    float v = 0.f;
    int qrow = q0 + r;
    if (qrow < QP) {
      int h = j >> 5;
      #pragma unroll
      for (int n = 0; n < 6; ++n)
        v += aw[((size_t)(b * 6 + n) * QP + qrow) * 128 + j] * cc[r][h][n];
    }
    xa[r][j] = v;
  }
  __syncthreads();
  // GEMM1: z = a@wo + bo + skip^T
  {
    const int j = t & 127;
    const int rg = t >> 7;
    float acc[8];
    #pragma unroll
    for (int r = 0; r < 8; ++r) acc[r] = 0.f;
    for (int d0 = 0; d0 < 128; d0 += 8) {
      float w8[8];
      #pragma unroll
      for (int i = 0; i < 8; ++i) w8[i] = wo[(d0 + i) * 128 + j];
      #pragma unroll
      for (int i = 0; i < 8; ++i) {
        const float w = w8[i];
        #pragma unroll
        for (int r = 0; r < 8; ++r) acc[r] += xa[rg * 8 + r][d0 + i] * w;
      }
    }
    const float bj = bo[j];
    #pragma unroll
    for (int r = 0; r < 8; ++r) {
      int qrow = q0 + rg * 8 + r;
      float sv = 0.f;
      if (qrow < QP) sv = skip[((size_t)b * 128 + j) * QP + qrow];
      zn[rg * 8 + r][j] = acc[r] + bj + sv;
    }
  }
  __syncthreads();
  if (t < 16) {
    float s = 0.f, s2 = 0.f;
    for (int d = 0; d < 128; ++d) { float v = zn[t][d]; s += v; s2 += v * v; }
    float mu = s * (1.f / 128.f);
    float var = s2 * (1.f / 128.f) - mu * mu;
    mu_s[t] = mu; rs_s[t] = rsqrtf(var + LNEPS);
  }
  __syncthreads();
  for (int idx = t; idx < 16 * 128; idx += 256) {
    int r = idx >> 7, j = idx & 127;
    zn[r][j] = (zn[r][j] - mu_s[r]) * rs_s[r] * lnpw[j] + lnpb[j];
  }
  __syncthreads();
  // GEMM2: h = gelu(zn@w1 + b1)
  {
    const int j = t;
    float acc[16];
    #pragma unroll
    for (int r = 0; r < 16; ++r) acc[r] = 0.f;
    for (int d0 = 0; d0 < 128; d0 += 8) {
      float w8[8];
      #pragma unroll
      for (int i = 0; i < 8; ++i) w8[i] = w1[(d0 + i) * 256 + j];
      #pragma unroll
      for (int i = 0; i < 8; ++i) {
        const float w = w8[i];
        #pragma unroll
        for (int r = 0; r < 16; ++r) acc[r] += zn[r][d0 + i] * w;
      }
    }
    const float bj = b1[j];
    #pragma unroll
    for (int r = 0; r < 16; ++r) {
      float x = acc[r] + bj;
      ht[r][j] = 0.5f * x * (1.f + erff(x * 0.70710678118654752f));
    }
  }
  __syncthreads();
  // GEMM3: z2 = h@w2 + b2 + zn
  {
    const int j = t & 127;
    const int rg = t >> 7;
    float acc[8];
    #pragma unroll
    for (int r = 0; r < 8; ++r) acc[r] = 0.f;
    for (int d0 = 0; d0 < 256; d0 += 8) {
      float w8[8];
      #pragma unroll
      for (int i = 0; i < 8; ++i) w8[i] = w2[(d0 + i) * 128 + j];
      #pragma unroll
      for (int i = 0; i < 8; ++i) {
        const float w = w8[i];
        #pragma unroll
        for (int r = 0; r < 8; ++r) acc[r] += ht[rg * 8 + r][d0 + i] * w;
      }
    }
    const float bj = b2[j];
    #pragma unroll
    for (int r = 0; r < 8; ++r)
      xa[rg * 8 + r][j] = acc[r] + bj + zn[rg * 8 + r][j];
  }
  __syncthreads();
  if (t < 16) {
    float s = 0.f, s2 = 0.f;
    for (int d = 0; d < 128; ++d) { float v = xa[t][d]; s += v; s2 += v * v; }
    float mu = s * (1.f / 128.f);
    float var = s2 * (1.f / 128.f) - mu * mu;
    mu_s[t] = mu; rs_s[t] = rsqrtf(var + LNEPS);
  }
  __syncthreads();
  for (int idx = t; idx < 16 * 128; idx += 256) {
    int j = idx >> 4, r = idx & 15;
    int qrow = q0 + r;
    if (qrow < QP) {
      float v = (xa[r][j] - mu_s[r]) * rs_s[r] * lnqw[j] + lnqb[j];
      out[((size_t)b * 128 + j) * QP + qrow] = v;
    }
  }
}

extern "C" void kernel_launch(void* const* d_in, const int* in_sizes, int n_in,
                              void* d_out, int out_size, void* d_ws, size_t ws_size,
                              hipStream_t stream) {
  const float* q       = (const float*)d_in[0];
  const float* k       = (const float*)d_in[1];
  const float* v       = (const float*)d_in[2];
  const float* skip    = (const float*)d_in[3];
  const float* ln_q_w  = (const float*)d_in[4];
  const float* ln_q_b  = (const float*)d_in[5];
  const float* wq      = (const float*)d_in[6];
  const float* bq      = (const float*)d_in[7];
  const float* ln_k_w  = (const float*)d_in[8];
  const float* ln_k_b  = (const float*)d_in[9];
  const float* wk      = (const float*)d_in[10];
  const float* bk      = (const float*)d_in[11];
  const float* ln_v_w  = (const float*)d_in[12];
  const float* ln_v_b  = (const float*)d_in[13];
  const float* wv      = (const float*)d_in[14];
  const float* bv      = (const float*)d_in[15];
  const float* wo      = (const float*)d_in[16];
  const float* bo      = (const float*)d_in[17];
  const float* ln_pre_w  = (const float*)d_in[18];
  const float* ln_pre_b  = (const float*)d_in[19];
  const float* w1      = (const float*)d_in[20];
  const float* b1      = (const float*)d_in[21];
  const float* w2      = (const float*)d_in[22];
  const float* b2      = (const float*)d_in[23];
  const float* ln_post_w = (const float*)d_in[24];
  const float* ln_post_b = (const float*)d_in[25];

  float* out = (float*)d_out;
  ushort* qhp = (ushort*)d_ws;             // 3,840,000 bf16
  ushort* khp = qhp + 3840000;             // 2,064,384 bf16
  ushort* vhp = khp + 2064384;             // 2,064,384 bf16
  ushort* wtq = vhp + 2064384;             // 16,384 bf16
  ushort* wtk = wtq + 16384;               // 16,384 bf16
  ushort* wtv = wtk + 16384;               // 16,384 bf16
  float*  aw  = (float*)(wtv + 16384);     // [bn][q][128] = 3,840,000 f32
  float*  ml  = aw + 3840000;              // [bn][q][h][2] = 240,000 f32

  wprep_kernel<<<dim3(16), 256, 0, stream>>>(wq, wtq);
  wprep_kernel<<<dim3(16), 256, 0, stream>>>(wk, wtk);
  wprep_kernel<<<dim3(16), 256, 0, stream>>>(wv, wtv);
  proj_kernel<<<dim3(40, 12), 256, 0, stream>>>(q, QP, ln_q_w, ln_q_b, wtq, bq, qhp, SCALE * LOG2E);
  proj_kernel<<<dim3(21, 12), 256, 0, stream>>>(k, KP, ln_k_w, ln_k_b, wtk, bk, khp, 1.0f);
  proj_kernel<<<dim3(21, 12), 256, 0, stream>>>(v, KP, ln_v_w, ln_v_b, wtv, bv, vhp, 1.0f);
  attn_kernel<<<dim3(40, 4, 12), 256, 0, stream>>>(qhp, khp, vhp, aw, ml);
  epilogue_kernel<<<dim3(157, 2), 256, 0, stream>>>(aw, ml, skip, wo, bo,
      ln_pre_w, ln_pre_b, w1, b1, w2, b2, ln_post_w, ln_post_b, out);
}